// Round 6
// baseline (992.303 us; speedup 1.0000x reference)
//
#include <hip/hip_runtime.h>
#include <math.h>

#define BB 8
#define TT 256
#define DD 256
#define HH 8
#define DHH 32
#define LL 4
#define DFF 1024
#define QTILE 16

// centers: linspace(0, 6.4, 128); delta = 6.4/127
#define RBF_DELTA 0.05039370078740158f
#define RBF_INVGAP 20.0f   // 1/0.05

// ---------------- temb: per-batch time embedding MLP -----------------
__global__ void temb_kernel(const float* __restrict__ timestep,
                            const float* __restrict__ t_w1, const float* __restrict__ t_b1,
                            const float* __restrict__ t_w2, const float* __restrict__ t_b2,
                            float* __restrict__ temb_out) {
    __shared__ float s0[128], s1[128];
    int b = blockIdx.x, j = threadIdx.x;
    float ts = timestep[b];
    const float LOG1E4 = 9.210340371976184f;
    if (j < 64) {
        float f = expf(-LOG1E4 * (float)j / 64.f);
        s0[j] = cosf(ts * f);
    } else {
        int i = j - 64;
        float f = expf(-LOG1E4 * (float)i / 64.f);
        s0[j] = sinf(ts * f);
    }
    __syncthreads();
    float acc = t_b1[j];
    for (int i = 0; i < 128; i++) acc += s0[i] * t_w1[i * 128 + j];
    acc = acc / (1.f + expf(-acc));   // silu
    s1[j] = acc;
    __syncthreads();
    float acc2 = t_b2[j];
    for (int i = 0; i < 128; i++) acc2 += s1[i] * t_w2[i * 128 + j];
    temb_out[b * 128 + j] = acc2;
}

// ---------------- embedding gather -----------------
__global__ void embed_kernel(const int* __restrict__ src, const float* __restrict__ emb,
                             float* __restrict__ x) {
    int r = blockIdx.x, d = threadIdx.x;
    x[r * DD + d] = emb[src[r] * DD + d];
}

// ---------------- LayerNorm: one row per block -----------------
__global__ void ln_kernel(const float* __restrict__ in, const float* __restrict__ g,
                          const float* __restrict__ bta, float* __restrict__ out) {
    __shared__ float red[8];
    __shared__ float mv[2];
    int r = blockIdx.x, t = threadIdx.x;
    float v = in[r * DD + t];
    float s = v, s2 = v * v;
    for (int off = 32; off > 0; off >>= 1) {
        s += __shfl_xor(s, off);
        s2 += __shfl_xor(s2, off);
    }
    int w = t >> 6;
    if ((t & 63) == 0) { red[w] = s; red[4 + w] = s2; }
    __syncthreads();
    if (t == 0) {
        float S = red[0] + red[1] + red[2] + red[3];
        float S2 = red[4] + red[5] + red[6] + red[7];
        float m = S * (1.f / 256.f);
        float var = S2 * (1.f / 256.f) - m * m;
        mv[0] = m; mv[1] = rsqrtf(var + 1e-6f);
    }
    __syncthreads();
    out[r * DD + t] = (v - mv[0]) * mv[1] * g[t] + bta[t];
}

// ---------------- f32 GEMM: C[M,N] = (A[M,K]@W[K,N] + bias)*scale (+relu) (+resid)
// tile 32(M) x 64(N), BK=16, 128 threads, 4x4 micro-tile
template <int RELU>
__global__ __launch_bounds__(128) void gemm_kernel(
    const float* __restrict__ A, const float* __restrict__ W,
    const float* __restrict__ bias, const float* __restrict__ resid,
    float* __restrict__ Cout, int N, int K, float scale) {
    __shared__ __align__(16) float As[16][36];  // [k][m], padded
    __shared__ __align__(16) float Bs[16][64];  // [k][n]
    int tx = threadIdx.x & 15;   // n group
    int ty = threadIdx.x >> 4;   // m group (0..7)
    int m0 = blockIdx.y * 32;
    int n0 = blockIdx.x * 64;
    float acc[4][4] = {};
    for (int k0 = 0; k0 < K; k0 += 16) {
        {   // A tile 32x16 -> transposed
            int row = threadIdx.x >> 2;
            int kk = (threadIdx.x & 3) << 2;
            const float4 av = *reinterpret_cast<const float4*>(&A[(m0 + row) * K + k0 + kk]);
            As[kk + 0][row] = av.x; As[kk + 1][row] = av.y;
            As[kk + 2][row] = av.z; As[kk + 3][row] = av.w;
        }
        {   // B tile 16x64
            int kk = threadIdx.x >> 4;
            int n = (threadIdx.x & 15) << 2;
            *reinterpret_cast<float4*>(&Bs[kk][n]) =
                *reinterpret_cast<const float4*>(&W[(k0 + kk) * N + n0 + n]);
            *reinterpret_cast<float4*>(&Bs[kk + 8][n]) =
                *reinterpret_cast<const float4*>(&W[(k0 + kk + 8) * N + n0 + n]);
        }
        __syncthreads();
#pragma unroll
        for (int kk = 0; kk < 16; kk++) {
            float4 a4 = *reinterpret_cast<const float4*>(&As[kk][ty * 4]);
            float4 b4 = *reinterpret_cast<const float4*>(&Bs[kk][tx * 4]);
            float av[4] = {a4.x, a4.y, a4.z, a4.w};
            float bv[4] = {b4.x, b4.y, b4.z, b4.w};
#pragma unroll
            for (int i = 0; i < 4; i++)
#pragma unroll
                for (int j = 0; j < 4; j++) acc[i][j] += av[i] * bv[j];
        }
        __syncthreads();
    }
#pragma unroll
    for (int i = 0; i < 4; i++) {
        int m = m0 + ty * 4 + i;
#pragma unroll
        for (int j = 0; j < 4; j++) {
            int n = n0 + tx * 4 + j;
            float v2 = (acc[i][j] + bias[n]) * scale;
            if (RELU) v2 = fmaxf(v2, 0.f);
            if (resid) v2 += resid[m * N + n];
            Cout[m * N + n] = v2;
        }
    }
}

// ---------------- fused attention: block per (qtile, h, b) -----------------
__global__ __launch_bounds__(256, 2) void attn_kernel(
    const float* __restrict__ qbuf, const float* __restrict__ kbuf,
    const float* __restrict__ vbuf, const float* __restrict__ u,
    const float* __restrict__ v, const float* __restrict__ temb,
    const float* __restrict__ bond, const int* __restrict__ lengths,
    float* __restrict__ ctx) {
    __shared__ float KV[256][33];        // K tile, later reused for V
    __shared__ float sc[QTILE][257];     // scores -> attn
    __shared__ float qu_s[QTILE][32], qv_s[QTILE][32];
    __shared__ float tq[QTILE];
    __shared__ float temb_s[32];

    int qt = blockIdx.x;   // 0..15
    int h  = blockIdx.y;   // 0..7
    int b  = blockIdx.z;   // 0..7
    int t  = threadIdx.x;
    int len = lengths[b];
    int q0 = qt * QTILE;

    // stage q fragments (+u, +v)
    for (int e = t; e < QTILE * 32; e += 256) {
        int q = e >> 5, dh = e & 31;
        float qs = qbuf[(b * TT + q0 + q) * DD + h * 32 + dh];
        qu_s[q][dh] = qs + u[h * 32 + dh];
        qv_s[q][dh] = qs + v[h * 32 + dh];
    }
    if (t < 32) temb_s[t] = (h >= 4) ? temb[b * 128 + (h - 4) * 32 + t] : 0.f;
    // stage K
    for (int e = t; e < 256 * 32; e += 256) {
        int k = e >> 5, dh = e & 31;
        KV[k][dh] = kbuf[(b * TT + k) * DD + h * 32 + dh];
    }
    __syncthreads();

    if (t < QTILE) {   // temb contribution for heads 4..7 (k-independent)
        float a = 0.f;
#pragma unroll
        for (int j = 0; j < 32; j++) a += qv_s[t][j] * temb_s[j];
        tq[t] = a;
    }
    __syncthreads();

    // ---- scores: thread t owns key k = t, loops q ----
    {
        int k = t;
        bool kvalid = k < len;
        float c0 = (float)(h * 32) * RBF_DELTA;
        for (int q = 0; q < QTILE; q++) {
            float s;
            if (!kvalid) {
                s = -1e18f;
            } else {
                float accA = 0.f;
#pragma unroll
                for (int dh = 0; dh < 32; dh++) accA += qu_s[q][dh] * KV[k][dh];
                float accB;
                if (h < 4) {
                    accB = 0.f;
                    if (q0 + q < len) {
                        float d = bond[(b * TT + q0 + q) * TT + k];
#pragma unroll
                        for (int j = 0; j < 32; j++) {
                            float diff = d - (c0 + j * RBF_DELTA);
                            accB += qv_s[q][j] * __expf(-diff * diff * RBF_INVGAP);
                        }
                    }
                } else {
                    accB = tq[q];
                }
                s = accA + accB;
            }
            sc[q][k] = s;
        }
    }
    __syncthreads();

    // ---- softmax: 16 threads per row ----
    {
        int r = t >> 4, j = t & 15;
        float vals[16];
        float mx = -1e30f;
#pragma unroll
        for (int i = 0; i < 16; i++) {
            vals[i] = sc[r][j + 16 * i];
            mx = fmaxf(mx, vals[i]);
        }
        for (int off = 8; off > 0; off >>= 1) mx = fmaxf(mx, __shfl_xor(mx, off));
        float sum = 0.f;
#pragma unroll
        for (int i = 0; i < 16; i++) {
            float e = __expf(vals[i] - mx);
            vals[i] = e; sum += e;
        }
        for (int off = 8; off > 0; off >>= 1) sum += __shfl_xor(sum, off);
        float inv = 1.f / sum;
#pragma unroll
        for (int i = 0; i < 16; i++) sc[r][j + 16 * i] = vals[i] * inv;
    }
    // restage V over K (no reader of KV between the barriers above/below)
    for (int e = t; e < 256 * 32; e += 256) {
        int k2 = e >> 5, dh = e & 31;
        KV[k2][dh] = vbuf[(b * TT + k2) * DD + h * 32 + dh];
    }
    __syncthreads();

    // ---- ctx = attn @ V ----
    {
        int dh = t & 31, qq = t >> 5;   // qq 0..7
#pragma unroll
        for (int rep = 0; rep < 2; rep++) {
            int q = qq + 8 * rep;
            float acc = 0.f;
#pragma unroll 8
            for (int k2 = 0; k2 < 256; k2++) acc += sc[q][k2] * KV[k2][dh];
            ctx[(b * TT + q0 + q) * DD + h * 32 + dh] = acc;
        }
    }
}

// ---------------- host launcher -----------------
extern "C" void kernel_launch(void* const* d_in, const int* in_sizes, int n_in,
                              void* d_out, int out_size, void* d_ws, size_t ws_size,
                              hipStream_t stream) {
    const int*   src      = (const int*)  d_in[0];
    const int*   lengths  = (const int*)  d_in[1];
    const float* bond     = (const float*)d_in[2];
    const float* timestep = (const float*)d_in[3];
    const float* emb      = (const float*)d_in[4];
    const float* t_w1     = (const float*)d_in[5];
    const float* t_b1     = (const float*)d_in[6];
    const float* t_w2     = (const float*)d_in[7];
    const float* t_b2     = (const float*)d_in[8];
    const float* u        = (const float*)d_in[9];
    const float* v        = (const float*)d_in[10];
    const float* Wq       = (const float*)d_in[11];
    const float* bq       = (const float*)d_in[12];
    const float* Wk       = (const float*)d_in[13];
    const float* bk       = (const float*)d_in[14];
    const float* Wv       = (const float*)d_in[15];
    const float* bv       = (const float*)d_in[16];
    const float* Wo       = (const float*)d_in[17];
    const float* bo       = (const float*)d_in[18];
    const float* ln1_g    = (const float*)d_in[19];
    const float* ln1_b    = (const float*)d_in[20];
    const float* ln2_g    = (const float*)d_in[21];
    const float* ln2_b    = (const float*)d_in[22];
    const float* ff_w1    = (const float*)d_in[23];
    const float* ff_b1    = (const float*)d_in[24];
    const float* ff_w2    = (const float*)d_in[25];
    const float* ff_b2    = (const float*)d_in[26];
    const float* lnf_g    = (const float*)d_in[27];
    const float* lnf_b    = (const float*)d_in[28];

    float* ws   = (float*)d_ws;
    float* xbuf = ws;                       // 2048*256
    float* hbuf = xbuf + 524288;
    float* qbuf = hbuf + 524288;
    float* kbuf = qbuf + 524288;
    float* vbuf = kbuf + 524288;
    float* cbuf = vbuf + 524288;
    float* obuf = cbuf + 524288;
    float* ffbuf = obuf + 524288;           // 2048*1024
    float* temb  = ffbuf + 2097152;         // 8*128

    temb_kernel<<<8, 128, 0, stream>>>(timestep, t_w1, t_b1, t_w2, t_b2, temb);
    embed_kernel<<<2048, 256, 0, stream>>>(src, emb, xbuf);

    const float scale = 0.17677669529663687f;  // 1/sqrt(32)
    dim3 g256(4, 64);     // N=256 gemms
    dim3 g1024(16, 64);   // N=1024 gemm

    for (int l = 0; l < LL; l++) {
        ln_kernel<<<2048, 256, 0, stream>>>(xbuf, ln1_g + l * 256, ln1_b + l * 256, hbuf);
        gemm_kernel<0><<<g256, 128, 0, stream>>>(hbuf, Wq + l * 65536, bq + l * 256, nullptr, qbuf, 256, 256, scale);
        gemm_kernel<0><<<g256, 128, 0, stream>>>(hbuf, Wk + l * 65536, bk + l * 256, nullptr, kbuf, 256, 256, 1.f);
        gemm_kernel<0><<<g256, 128, 0, stream>>>(hbuf, Wv + l * 65536, bv + l * 256, nullptr, vbuf, 256, 256, 1.f);
        attn_kernel<<<dim3(16, 8, 8), 256, 0, stream>>>(qbuf, kbuf, vbuf, u, v, temb, bond, lengths, cbuf);
        gemm_kernel<0><<<g256, 128, 0, stream>>>(cbuf, Wo + l * 65536, bo + l * 256, xbuf, obuf, 256, 256, 1.f);
        ln_kernel<<<2048, 256, 0, stream>>>(obuf, ln2_g + l * 256, ln2_b + l * 256, hbuf);
        gemm_kernel<1><<<g1024, 128, 0, stream>>>(hbuf, ff_w1 + l * 262144, ff_b1 + l * 1024, nullptr, ffbuf, 1024, 256, 1.f);
        gemm_kernel<0><<<g256, 128, 0, stream>>>(ffbuf, ff_w2 + l * 262144, ff_b2 + l * 256, obuf, xbuf, 256, 1024, 1.f);
    }
    ln_kernel<<<2048, 256, 0, stream>>>(xbuf, lnf_g, lnf_b, (float*)d_out);
}

// Round 8
// 699.961 us; speedup vs baseline: 1.4177x; 1.4177x over previous
//
#include <hip/hip_runtime.h>
#include <math.h>

#define BB 8
#define TT 256
#define DD 256
#define HH 8
#define DHH 32
#define LL 4
#define DFF 1024
#define QTILE 16

// centers: linspace(0, 6.4, 128); delta = 6.4/127
#define RBF_DELTA 0.05039370078740158f
#define RBF_INVGAP 20.0f   // 1/0.05

// ---------------- temb: per-batch time embedding MLP -----------------
__global__ void temb_kernel(const float* __restrict__ timestep,
                            const float* __restrict__ t_w1, const float* __restrict__ t_b1,
                            const float* __restrict__ t_w2, const float* __restrict__ t_b2,
                            float* __restrict__ temb_out) {
    __shared__ float s0[128], s1[128];
    int b = blockIdx.x, j = threadIdx.x;
    float ts = timestep[b];
    const float LOG1E4 = 9.210340371976184f;
    if (j < 64) {
        float f = expf(-LOG1E4 * (float)j / 64.f);
        s0[j] = cosf(ts * f);
    } else {
        int i = j - 64;
        float f = expf(-LOG1E4 * (float)i / 64.f);
        s0[j] = sinf(ts * f);
    }
    __syncthreads();
    float acc = t_b1[j];
    for (int i = 0; i < 128; i++) acc += s0[i] * t_w1[i * 128 + j];
    acc = acc / (1.f + expf(-acc));   // silu
    s1[j] = acc;
    __syncthreads();
    float acc2 = t_b2[j];
    for (int i = 0; i < 128; i++) acc2 += s1[i] * t_w2[i * 128 + j];
    temb_out[b * 128 + j] = acc2;
}

// ---------------- embedding gather -----------------
__global__ void embed_kernel(const int* __restrict__ src, const float* __restrict__ emb,
                             float* __restrict__ x) {
    int r = blockIdx.x, d = threadIdx.x;
    x[r * DD + d] = emb[src[r] * DD + d];
}

// ---------------- LayerNorm: one row per block -----------------
__global__ void ln_kernel(const float* __restrict__ in, const float* __restrict__ g,
                          const float* __restrict__ bta, float* __restrict__ out) {
    __shared__ float red[8];
    __shared__ float mv[2];
    int r = blockIdx.x, t = threadIdx.x;
    float v = in[r * DD + t];
    float s = v, s2 = v * v;
    for (int off = 32; off > 0; off >>= 1) {
        s += __shfl_xor(s, off);
        s2 += __shfl_xor(s2, off);
    }
    int w = t >> 6;
    if ((t & 63) == 0) { red[w] = s; red[4 + w] = s2; }
    __syncthreads();
    if (t == 0) {
        float S = red[0] + red[1] + red[2] + red[3];
        float S2 = red[4] + red[5] + red[6] + red[7];
        float m = S * (1.f / 256.f);
        float var = S2 * (1.f / 256.f) - m * m;
        mv[0] = m; mv[1] = rsqrtf(var + 1e-6f);
    }
    __syncthreads();
    out[r * DD + t] = (v - mv[0]) * mv[1] * g[t] + bta[t];
}

// ---------------- f32 GEMM v2: in-block split-K x4, 512 threads -------------
// C[M,N] = (A[M,K]@W[K,N] + bias)*scale (+relu) (+resid)
// tile 32(M) x 64(N), BK=64 shared LDS tile; wave-group g handles k-slices
// [g*16, g*16+16); group accs reduced through LDS (aliased over tile space).
// blocks = (N/64, M/32 [, Z]); 512 thr = 8 waves.
__device__ __forceinline__ void gemm_body(
    const float* __restrict__ A, const float* __restrict__ W,
    const float* __restrict__ bias, const float* __restrict__ resid,
    float* __restrict__ Cout, int N, int K, float scale, int RELU) {
    __shared__ __align__(16) float smem[6656];   // As[64][36] | Bs[64][68]; red aliased
    float* As = smem;            // stride 36
    float* Bs = smem + 2304;     // stride 68
    float* red = smem;           // [3][2048] after final barrier

    int tid = threadIdx.x;
    int g  = tid >> 7;        // wave-group 0..3
    int t  = tid & 127;
    int tx = t & 15;          // n group
    int ty = t >> 4;          // m group
    int m0 = blockIdx.y * 32;
    int n0 = blockIdx.x * 64;

    float acc[4][4] = {};
    for (int k0 = 0; k0 < K; k0 += 64) {
        {   // stage A 32(m) x 64(k), transposed -> As[k][m]
            int m  = tid >> 4;          // 0..31
            int k4 = (tid & 15) << 2;   // 0..60
            const float4 av = *reinterpret_cast<const float4*>(&A[(m0 + m) * K + k0 + k4]);
            As[(k4 + 0) * 36 + m] = av.x;
            As[(k4 + 1) * 36 + m] = av.y;
            As[(k4 + 2) * 36 + m] = av.z;
            As[(k4 + 3) * 36 + m] = av.w;
        }
        {   // stage B 64(k) x 64(n)
            int r = tid >> 4;           // 0..31
            int c = (tid & 15) << 2;
            *reinterpret_cast<float4*>(&Bs[r * 68 + c]) =
                *reinterpret_cast<const float4*>(&W[(k0 + r) * N + n0 + c]);
            *reinterpret_cast<float4*>(&Bs[(r + 32) * 68 + c]) =
                *reinterpret_cast<const float4*>(&W[(k0 + r + 32) * N + n0 + c]);
        }
        __syncthreads();
#pragma unroll
        for (int kk = 0; kk < 16; kk++) {
            int k = (g << 4) + kk;
            float4 a4 = *reinterpret_cast<const float4*>(&As[k * 36 + (ty << 2)]);
            float4 b4 = *reinterpret_cast<const float4*>(&Bs[k * 68 + (tx << 2)]);
            float av[4] = {a4.x, a4.y, a4.z, a4.w};
            float bv[4] = {b4.x, b4.y, b4.z, b4.w};
#pragma unroll
            for (int i = 0; i < 4; i++)
#pragma unroll
                for (int j = 0; j < 4; j++) acc[i][j] += av[i] * bv[j];
        }
        __syncthreads();
    }
    // cross-group reduction (red aliases As/Bs space — safe after barrier)
    if (g > 0) {
        float* r0 = &red[(g - 1) * 2048 + t * 16];
#pragma unroll
        for (int i = 0; i < 4; i++)
            *reinterpret_cast<float4*>(&r0[i * 4]) =
                make_float4(acc[i][0], acc[i][1], acc[i][2], acc[i][3]);
    }
    __syncthreads();
    if (g == 0) {
        const float* r0 = &red[t * 16];
#pragma unroll
        for (int i = 0; i < 4; i++) {
            int m = m0 + (ty << 2) + i;
            float4 ov;
            float* po = &ov.x;
#pragma unroll
            for (int j = 0; j < 4; j++) {
                int idx = i * 4 + j;
                float v2 = acc[i][j] + r0[idx] + r0[2048 + idx] + r0[4096 + idx];
                int n = n0 + (tx << 2) + j;
                v2 = (v2 + bias[n]) * scale;
                if (RELU) v2 = fmaxf(v2, 0.f);
                if (resid) v2 += resid[m * N + n];
                po[j] = v2;
            }
            *reinterpret_cast<float4*>(&Cout[m * N + n0 + (tx << 2)]) = ov;
        }
    }
}

template <int RELU>
__global__ __launch_bounds__(512) void gemm_kernel(
    const float* __restrict__ A, const float* __restrict__ W,
    const float* __restrict__ bias, const float* __restrict__ resid,
    float* __restrict__ Cout, int N, int K, float scale) {
    gemm_body(A, W, bias, resid, Cout, N, K, scale, RELU);
}

// fused Q/K/V: blockIdx.z selects weight/bias/output/scale
__global__ __launch_bounds__(512) void qkv_kernel(
    const float* __restrict__ A,
    const float* __restrict__ Wq, const float* __restrict__ bq, float* __restrict__ qo,
    const float* __restrict__ Wk, const float* __restrict__ bk, float* __restrict__ ko,
    const float* __restrict__ Wv, const float* __restrict__ bv, float* __restrict__ vo,
    float qscale) {
    int z = blockIdx.z;
    const float* W = (z == 0) ? Wq : (z == 1) ? Wk : Wv;
    const float* bi = (z == 0) ? bq : (z == 1) ? bk : bv;
    float* o = (z == 0) ? qo : (z == 1) ? ko : vo;
    float sc = (z == 0) ? qscale : 1.f;
    gemm_body(A, W, bi, nullptr, o, DD, DD, sc, 0);
}

// ---------------- fused attention: block per (qtile, h, b) -----------------
__global__ __launch_bounds__(256, 2) void attn_kernel(
    const float* __restrict__ qbuf, const float* __restrict__ kbuf,
    const float* __restrict__ vbuf, const float* __restrict__ u,
    const float* __restrict__ v, const float* __restrict__ temb,
    const float* __restrict__ bond, const int* __restrict__ lengths,
    float* __restrict__ ctx) {
    __shared__ float KV[256][33];        // K tile, later reused for V
    __shared__ float sc[QTILE][257];     // scores -> attn
    __shared__ float qu_s[QTILE][32], qv_s[QTILE][32];
    __shared__ float tq[QTILE];
    __shared__ float temb_s[32];

    int qt = blockIdx.x;   // 0..15
    int h  = blockIdx.y;   // 0..7
    int b  = blockIdx.z;   // 0..7
    int t  = threadIdx.x;
    int len = lengths[b];
    int q0 = qt * QTILE;

    // stage q fragments (+u, +v)
    for (int e = t; e < QTILE * 32; e += 256) {
        int q = e >> 5, dh = e & 31;
        float qs = qbuf[(b * TT + q0 + q) * DD + h * 32 + dh];
        qu_s[q][dh] = qs + u[h * 32 + dh];
        qv_s[q][dh] = qs + v[h * 32 + dh];
    }
    if (t < 32) temb_s[t] = (h >= 4) ? temb[b * 128 + (h - 4) * 32 + t] : 0.f;
    // stage K
    for (int e = t; e < 256 * 32; e += 256) {
        int k = e >> 5, dh = e & 31;
        KV[k][dh] = kbuf[(b * TT + k) * DD + h * 32 + dh];
    }
    __syncthreads();

    if (t < QTILE) {   // temb contribution for heads 4..7 (k-independent)
        float a = 0.f;
#pragma unroll
        for (int j = 0; j < 32; j++) a += qv_s[t][j] * temb_s[j];
        tq[t] = a;
    }
    __syncthreads();

    // ---- scores: thread t owns key k = t, loops q ----
    {
        int k = t;
        bool kvalid = k < len;
        float c0 = (float)(h * 32) * RBF_DELTA;
        for (int q = 0; q < QTILE; q++) {
            float s;
            if (!kvalid) {
                s = -1e18f;
            } else {
                float accA = 0.f;
#pragma unroll
                for (int dh = 0; dh < 32; dh++) accA += qu_s[q][dh] * KV[k][dh];
                float accB;
                if (h < 4) {
                    accB = 0.f;
                    if (q0 + q < len) {
                        float d = bond[(b * TT + q0 + q) * TT + k];
#pragma unroll
                        for (int j = 0; j < 32; j++) {
                            float diff = d - (c0 + j * RBF_DELTA);
                            accB += qv_s[q][j] * __expf(-diff * diff * RBF_INVGAP);
                        }
                    }
                } else {
                    accB = tq[q];
                }
                s = accA + accB;
            }
            sc[q][k] = s;
        }
    }
    __syncthreads();

    // ---- softmax: 16 threads per row ----
    {
        int r = t >> 4, j = t & 15;
        float vals[16];
        float mx = -1e30f;
#pragma unroll
        for (int i = 0; i < 16; i++) {
            vals[i] = sc[r][j + 16 * i];
            mx = fmaxf(mx, vals[i]);
        }
        for (int off = 8; off > 0; off >>= 1) mx = fmaxf(mx, __shfl_xor(mx, off));
        float sum = 0.f;
#pragma unroll
        for (int i = 0; i < 16; i++) {
            float e = __expf(vals[i] - mx);
            vals[i] = e; sum += e;
        }
        for (int off = 8; off > 0; off >>= 1) sum += __shfl_xor(sum, off);
        float inv = 1.f / sum;
#pragma unroll
        for (int i = 0; i < 16; i++) sc[r][j + 16 * i] = vals[i] * inv;
    }
    // restage V over K (no reader of KV between the barriers above/below)
    for (int e = t; e < 256 * 32; e += 256) {
        int k2 = e >> 5, dh = e & 31;
        KV[k2][dh] = vbuf[(b * TT + k2) * DD + h * 32 + dh];
    }
    __syncthreads();

    // ---- ctx = attn @ V ----
    {
        int dh = t & 31, qq = t >> 5;   // qq 0..7
#pragma unroll
        for (int rep = 0; rep < 2; rep++) {
            int q = qq + 8 * rep;
            float acc = 0.f;
#pragma unroll 8
            for (int k2 = 0; k2 < 256; k2++) acc += sc[q][k2] * KV[k2][dh];
            ctx[(b * TT + q0 + q) * DD + h * 32 + dh] = acc;
        }
    }
}

// ---------------- host launcher -----------------
extern "C" void kernel_launch(void* const* d_in, const int* in_sizes, int n_in,
                              void* d_out, int out_size, void* d_ws, size_t ws_size,
                              hipStream_t stream) {
    const int*   src      = (const int*)  d_in[0];
    const int*   lengths  = (const int*)  d_in[1];
    const float* bond     = (const float*)d_in[2];
    const float* timestep = (const float*)d_in[3];
    const float* emb      = (const float*)d_in[4];
    const float* t_w1     = (const float*)d_in[5];
    const float* t_b1     = (const float*)d_in[6];
    const float* t_w2     = (const float*)d_in[7];
    const float* t_b2     = (const float*)d_in[8];
    const float* u        = (const float*)d_in[9];
    const float* v        = (const float*)d_in[10];
    const float* Wq       = (const float*)d_in[11];
    const float* bq       = (const float*)d_in[12];
    const float* Wk       = (const float*)d_in[13];
    const float* bk       = (const float*)d_in[14];
    const float* Wv       = (const float*)d_in[15];
    const float* bv       = (const float*)d_in[16];
    const float* Wo       = (const float*)d_in[17];
    const float* bo       = (const float*)d_in[18];
    const float* ln1_g    = (const float*)d_in[19];
    const float* ln1_b    = (const float*)d_in[20];
    const float* ln2_g    = (const float*)d_in[21];
    const float* ln2_b    = (const float*)d_in[22];
    const float* ff_w1    = (const float*)d_in[23];
    const float* ff_b1    = (const float*)d_in[24];
    const float* ff_w2    = (const float*)d_in[25];
    const float* ff_b2    = (const float*)d_in[26];
    const float* lnf_g    = (const float*)d_in[27];
    const float* lnf_b    = (const float*)d_in[28];

    float* ws   = (float*)d_ws;
    float* xbuf = ws;                       // 2048*256
    float* hbuf = xbuf + 524288;
    float* qbuf = hbuf + 524288;
    float* kbuf = qbuf + 524288;
    float* vbuf = kbuf + 524288;
    float* cbuf = vbuf + 524288;
    float* obuf = cbuf + 524288;
    float* ffbuf = obuf + 524288;           // 2048*1024
    float* temb  = ffbuf + 2097152;         // 8*128

    temb_kernel<<<8, 128, 0, stream>>>(timestep, t_w1, t_b1, t_w2, t_b2, temb);
    embed_kernel<<<2048, 256, 0, stream>>>(src, emb, xbuf);

    const float scale = 0.17677669529663687f;  // 1/sqrt(32)
    dim3 gqkv(4, 64, 3);  // N=256 x3
    dim3 g256(4, 64);     // N=256 gemms
    dim3 g1024(16, 64);   // N=1024 gemm

    for (int l = 0; l < LL; l++) {
        ln_kernel<<<2048, 256, 0, stream>>>(xbuf, ln1_g + l * 256, ln1_b + l * 256, hbuf);
        qkv_kernel<<<gqkv, 512, 0, stream>>>(hbuf,
            Wq + l * 65536, bq + l * 256, qbuf,
            Wk + l * 65536, bk + l * 256, kbuf,
            Wv + l * 65536, bv + l * 256, vbuf, scale);
        attn_kernel<<<dim3(16, 8, 8), 256, 0, stream>>>(qbuf, kbuf, vbuf, u, v, temb, bond, lengths, cbuf);
        gemm_kernel<0><<<g256, 512, 0, stream>>>(cbuf, Wo + l * 65536, bo + l * 256, xbuf, obuf, 256, 256, 1.f);
        ln_kernel<<<2048, 256, 0, stream>>>(obuf, ln2_g + l * 256, ln2_b + l * 256, hbuf);
        gemm_kernel<1><<<g1024, 512, 0, stream>>>(hbuf, ff_w1 + l * 262144, ff_b1 + l * 1024, nullptr, ffbuf, 1024, 256, 1.f);
        gemm_kernel<0><<<g256, 512, 0, stream>>>(ffbuf, ff_w2 + l * 262144, ff_b2 + l * 256, obuf, xbuf, 256, 1024, 1.f);
    }
    ln_kernel<<<2048, 256, 0, stream>>>(xbuf, lnf_g, lnf_b, (float*)d_out);
}